// Round 4
// baseline (133.169 us; speedup 1.0000x reference)
//
#include <hip/hip_runtime.h>

// UCBNorm, 3 kernels, NO atomics / NO memset / NO cooperative launch.
//
// Math (softmax(prior) over size-1 axis == 1 -> only constant 1/sqrt(1+EPS)):
//   p   = exp(-0.5*(x-m)^2/(softplus(v)+EPS)),  den = EPS + sum_k p
//   tau = p/den,  S[k,d] = EPS + sum_{b,t} tau
//   e[k,b,d]   = (sum_t tau*x)/(T*S)
//   var[k,b,d] = (sum_t tau^3*x^2)/(T*S^3)
//   out[b,t,d] = (1/sqrt(1+EPS)) * sum_k tau*(x-e)*rsqrt(var+EPS)
//
// p1: block = (b, 64-d slice, 64-t chunk); per-(k,b,tc,d) partial sums are
//     block-local (LDS tree over 4 waves), plain stores to unique slots.
// fin: reduce 8 t-chunks + 16 b thread-locally; emit [B][D][K][2] (e,r).
// p2: recompute tau, write out.

namespace {
constexpr int K = 8, B = 16, T = 512, D = 256;
constexpr float EPS = 1e-3f;
constexpr int TC  = 8;            // t-chunks in pass1
constexpr int TCL = T / TC;       // 64 t per chunk
constexpr int DGA = 4;            // d-groups (64 d each)
constexpr int TPA = 4;            // t-parallel waves per block
constexpr int RTA = TCL / TPA;    // 16 rows per thread
constexpr int KS  = 3 * K;        // 24 (k,stat)
constexpr int PSZ = K * B * TC * D;  // 262144 floats per partial array
}

__global__ __launch_bounds__(256) void ucb_p1(
    const float* __restrict__ x, const float* __restrict__ mean,
    const float* __restrict__ variance,
    float* __restrict__ pt, float* __restrict__ p1, float* __restrict__ p3)
{
  __shared__ float red[TPA][64][KS + 1];   // stride 25: conflict-free

  const int tid = threadIdx.x;
  const int dl  = tid & 63;                // lane = d
  const int tp  = tid >> 6;                // wave = t-phase
  const int bi  = blockIdx.x;
  const int b   = bi >> 5;                 // /32
  const int dg  = (bi >> 3) & 3;
  const int tc  = bi & 7;
  const int dd  = dg * 64 + dl;

  float m[K], nh[K];
#pragma unroll
  for (int k = 0; k < K; ++k) {
    m[k] = mean[k*D + dd];
    float sp = log1pf(__expf(variance[k*D + dd]));   // softplus
    nh[k] = -0.5f / (sp + EPS);
  }

  float ast[K], as1[K], as3[K];
#pragma unroll
  for (int k = 0; k < K; ++k) { ast[k] = 0.f; as1[k] = 0.f; as3[k] = 0.f; }

  const float* xp = x + ((size_t)b*T + (size_t)tc*TCL + tp)*D + dd;
#pragma unroll 4
  for (int j = 0; j < RTA; ++j) {
    float xv = xp[(size_t)j*TPA*D];
    float p[K];
    float den = EPS;
#pragma unroll
    for (int k = 0; k < K; ++k) {
      float df = xv - m[k];
      p[k] = __expf(nh[k]*df*df);
      den += p[k];
    }
    float rden = __builtin_amdgcn_rcpf(den);
#pragma unroll
    for (int k = 0; k < K; ++k) {
      float tau = p[k]*rden;
      float tx  = tau*xv;
      ast[k] += tau;
      as1[k] += tx;
      as3[k] += tau*tx*tx;           // tau^3 x^2
    }
  }

#pragma unroll
  for (int k = 0; k < K; ++k) {
    red[tp][dl][3*k+0] = ast[k];
    red[tp][dl][3*k+1] = as1[k];
    red[tp][dl][3*k+2] = as3[k];
  }
  __syncthreads();

#pragma unroll
  for (int i = 0; i < 6; ++i) {           // 1536 items, wave-uniform ks
    const int item = tid + i*256;
    const int dloc = item & 63;
    const int ks   = item >> 6;           // 0..23
    float s = red[0][dloc][ks] + red[1][dloc][ks]
            + red[2][dloc][ks] + red[3][dloc][ks];
    const int k = ks / 3, stat = ks % 3;
    const size_t idx = ((size_t)((k*B + b)*TC + tc))*D + dg*64 + dloc;
    if      (stat == 0) pt[idx] = s;
    else if (stat == 1) p1[idx] = s;
    else                p3[idx] = s;
  }
}

__global__ __launch_bounds__(64) void ucb_fin(
    const float* __restrict__ pt, const float* __restrict__ p1,
    const float* __restrict__ p3, float* __restrict__ er)   // er: [B][D][K][2]
{
  const int k = blockIdx.x >> 2;
  const int d = (blockIdx.x & 3)*64 + threadIdx.x;

  float s1b[B], s3b[B];
  float stt = 0.f;
#pragma unroll
  for (int b = 0; b < B; ++b) {
    float a0 = 0.f, a1 = 0.f, a3 = 0.f;
#pragma unroll
    for (int tc = 0; tc < TC; ++tc) {
      const size_t idx = ((size_t)((k*B + b)*TC + tc))*D + d;
      a0 += pt[idx]; a1 += p1[idx]; a3 += p3[idx];
    }
    stt += a0; s1b[b] = a1; s3b[b] = a3;
  }
  const float rS = 1.0f / (stt + EPS);
  const float rT = 1.0f / T;
#pragma unroll
  for (int b = 0; b < B; ++b) {
    float e  = s1b[b] * rT * rS;
    float vv = s3b[b] * rT * (rS*rS*rS);
    float r  = rsqrtf(vv + EPS);
    er[((size_t)b*D + d)*16 + 2*k]     = e;
    er[((size_t)b*D + d)*16 + 2*k + 1] = r;
  }
}

__global__ __launch_bounds__(256) void ucb_p2(
    const float* __restrict__ x, const float* __restrict__ mean,
    const float* __restrict__ variance, const float* __restrict__ er,
    float* __restrict__ out)
{
  const int d  = threadIdx.x;
  const int b  = blockIdx.x >> 5;
  const int tc = blockIdx.x & 31;          // 32 chunks x 16 t

  float m[K], nh[K], e[K], r[K];
#pragma unroll
  for (int k = 0; k < K; ++k) {
    m[k] = mean[k*D + d];
    float sp = log1pf(__expf(variance[k*D + d]));
    nh[k] = -0.5f / (sp + EPS);
  }
  const float4* ep = (const float4*)(er + ((size_t)b*D + d)*16);
#pragma unroll
  for (int q = 0; q < 4; ++q) {
    float4 v = ep[q];
    e[2*q]   = v.x; r[2*q]   = v.y;
    e[2*q+1] = v.z; r[2*q+1] = v.w;
  }

  const float isp = 0.99950037f;           // 1/sqrt(1+EPS)
  const size_t base = ((size_t)b*T + (size_t)tc*16)*D + d;
#pragma unroll 4
  for (int t = 0; t < 16; ++t) {
    float xv = x[base + (size_t)t*D];
    float p[K];
    float den = EPS;
#pragma unroll
    for (int k = 0; k < K; ++k) {
      float df = xv - m[k];
      p[k] = __expf(nh[k]*df*df);
      den += p[k];
    }
    float rden = __builtin_amdgcn_rcpf(den);
    float acc = 0.f;
#pragma unroll
    for (int k = 0; k < K; ++k)
      acc += p[k] * (xv - e[k]) * r[k];
    out[base + (size_t)t*D] = acc * rden * isp;
  }
}

extern "C" void kernel_launch(void* const* d_in, const int* in_sizes, int n_in,
                              void* d_out, int out_size, void* d_ws, size_t ws_size,
                              hipStream_t stream) {
  const float* x        = (const float*)d_in[0];
  const float* mean     = (const float*)d_in[1];
  const float* variance = (const float*)d_in[2];
  // d_in[3] (prior): softmax over size-1 axis == 1 -> constant baked in.

  float* out = (float*)d_out;
  float* w   = (float*)d_ws;
  float* pt  = w;            // [K][B][TC][D] = 262144 floats
  float* p1  = pt + PSZ;
  float* p3  = p1 + PSZ;
  float* er  = p3 + PSZ;     // [B][D][K][2] = 65536 floats
  // every ws element is written before it is read -> no memset needed

  ucb_p1<<<B*DGA*TC, 256, 0, stream>>>(x, mean, variance, pt, p1, p3);
  ucb_fin<<<K*4, 64, 0, stream>>>(pt, p1, p3, er);
  ucb_p2<<<B*32, 256, 0, stream>>>(x, mean, variance, er, out);
}

// Round 5
// 91.780 us; speedup vs baseline: 1.4510x; 1.4510x over previous
//
#include <hip/hip_runtime.h>

// UCBNorm, 3 kernels, NO atomics / NO memset / NO cooperative launch.
//
// Math (softmax(prior) over size-1 axis == 1 -> only constant 1/sqrt(1+EPS)):
//   p   = exp(-0.5*(x-m)^2/(softplus(v)+EPS)),  den = EPS + sum_k p
//   tau = p/den,  S[k,d] = EPS + sum_{b,t} tau
//   e[k,b,d]   = (sum_t tau*x)/(T*S)
//   var[k,b,d] = (sum_t tau^3*x^2)/(T*S^3)
//   out[b,t,d] = (1/sqrt(1+EPS)) * sum_k tau*(x-e)*rsqrt(var+EPS)
//
// p1:  1024 blocks (b, 64-d slice, 32-t chunk); block-local LDS reduce,
//      plain stores to unique [K][B][TC][D] slots.
// fin: 128 blocks, one thread per (k,b,d); cross-b S via 16-wide LDS reduce.
// p2:  1024 blocks (b, 8-t chunk) x 256 d; recompute tau, write out.

namespace {
constexpr int K = 8, B = 16, T = 512, D = 256;
constexpr float EPS = 1e-3f;
constexpr int TC  = 16;           // t-chunks in pass1
constexpr int TCL = T / TC;       // 32 t per chunk
constexpr int TPA = 4;            // t-parallel waves per block
constexpr int RTA = TCL / TPA;    // 8 rows per thread
constexpr int KS  = 3 * K;        // 24 (k,stat)
constexpr int PSZ = K * B * TC * D;  // 524288 floats per partial array
}

__global__ __launch_bounds__(256) void ucb_p1(
    const float* __restrict__ x, const float* __restrict__ mean,
    const float* __restrict__ variance,
    float* __restrict__ pt, float* __restrict__ p1, float* __restrict__ p3)
{
  __shared__ float red[TPA][64][KS + 1];   // stride 25: conflict-free

  const int tid = threadIdx.x;
  const int dl  = tid & 63;                // lane = d
  const int tp  = tid >> 6;                // wave = t-phase
  const int bi  = blockIdx.x;
  const int b   = bi >> 6;                 // 4 dg * 16 tc = 64 per b
  const int dg  = (bi >> 4) & 3;
  const int tc  = bi & 15;
  const int dd  = dg * 64 + dl;

  float m[K], nh[K];
#pragma unroll
  for (int k = 0; k < K; ++k) {
    m[k] = mean[k*D + dd];
    float sp = log1pf(__expf(variance[k*D + dd]));   // softplus
    nh[k] = -0.5f / (sp + EPS);
  }

  float ast[K], as1[K], as3[K];
#pragma unroll
  for (int k = 0; k < K; ++k) { ast[k] = 0.f; as1[k] = 0.f; as3[k] = 0.f; }

  const float* xp = x + ((size_t)b*T + (size_t)tc*TCL + tp)*D + dd;
#pragma unroll
  for (int j = 0; j < RTA; ++j) {
    float xv = xp[(size_t)j*TPA*D];
    float p[K];
    float den = EPS;
#pragma unroll
    for (int k = 0; k < K; ++k) {
      float df = xv - m[k];
      p[k] = __expf(nh[k]*df*df);
      den += p[k];
    }
    float rden = __builtin_amdgcn_rcpf(den);
#pragma unroll
    for (int k = 0; k < K; ++k) {
      float tau = p[k]*rden;
      float tx  = tau*xv;
      ast[k] += tau;
      as1[k] += tx;
      as3[k] += tau*tx*tx;           // tau^3 x^2
    }
  }

#pragma unroll
  for (int k = 0; k < K; ++k) {
    red[tp][dl][3*k+0] = ast[k];
    red[tp][dl][3*k+1] = as1[k];
    red[tp][dl][3*k+2] = as3[k];
  }
  __syncthreads();

#pragma unroll
  for (int i = 0; i < 6; ++i) {           // 1536 items, wave-uniform ks
    const int item = tid + i*256;
    const int dloc = item & 63;
    const int ks   = item >> 6;           // 0..23
    float s = red[0][dloc][ks] + red[1][dloc][ks]
            + red[2][dloc][ks] + red[3][dloc][ks];
    const int k = ks / 3, stat = ks % 3;
    const size_t idx = ((size_t)((k*B + b)*TC + tc))*D + dg*64 + dloc;
    if      (stat == 0) pt[idx] = s;
    else if (stat == 1) p1[idx] = s;
    else                p3[idx] = s;
  }
}

__global__ __launch_bounds__(256) void ucb_fin(
    const float* __restrict__ pt, const float* __restrict__ p1,
    const float* __restrict__ p3, float* __restrict__ er)   // er: [B][D][K][2]
{
  // grid: K * (D/16) = 128 blocks; threads: 16 b x 16 d
  __shared__ float reds[B][17];

  const int k  = blockIdx.x >> 4;
  const int d0 = (blockIdx.x & 15) * 16;
  const int dl = threadIdx.x & 15;
  const int b  = threadIdx.x >> 4;
  const int d  = d0 + dl;

  float a0 = 0.f, a1 = 0.f, a3 = 0.f;
  const size_t base = ((size_t)(k*B + b)*TC)*D + d;
#pragma unroll
  for (int tc = 0; tc < TC; ++tc) {
    a0 += pt[base + (size_t)tc*D];
    a1 += p1[base + (size_t)tc*D];
    a3 += p3[base + (size_t)tc*D];
  }
  reds[b][dl] = a0;
  __syncthreads();
  if (b == 0) {                      // 16 lanes: cross-b sum for S
    float s = 0.f;
#pragma unroll
    for (int bb = 0; bb < B; ++bb) s += reds[bb][dl];
    reds[0][dl] = 1.0f / (s + EPS);  // rS
  }
  __syncthreads();

  const float rS = reds[0][dl];
  const float rT = 1.0f / T;
  const float e  = a1 * rT * rS;
  const float vv = a3 * rT * (rS*rS*rS);
  const float r  = rsqrtf(vv + EPS);
  *(float2*)(er + ((size_t)b*D + d)*16 + 2*k) = make_float2(e, r);
}

__global__ __launch_bounds__(256) void ucb_p2(
    const float* __restrict__ x, const float* __restrict__ mean,
    const float* __restrict__ variance, const float* __restrict__ er,
    float* __restrict__ out)
{
  const int d  = threadIdx.x;
  const int b  = blockIdx.x >> 6;
  const int tc = blockIdx.x & 63;          // 64 chunks x 8 t

  float m[K], nh[K], e[K], r[K];
#pragma unroll
  for (int k = 0; k < K; ++k) {
    m[k] = mean[k*D + d];
    float sp = log1pf(__expf(variance[k*D + d]));
    nh[k] = -0.5f / (sp + EPS);
  }
  const float4* ep = (const float4*)(er + ((size_t)b*D + d)*16);
#pragma unroll
  for (int q = 0; q < 4; ++q) {
    float4 v = ep[q];
    e[2*q]   = v.x; r[2*q]   = v.y;
    e[2*q+1] = v.z; r[2*q+1] = v.w;
  }

  const float isp = 0.99950037f;           // 1/sqrt(1+EPS)
  const size_t base = ((size_t)b*T + (size_t)tc*8)*D + d;
#pragma unroll
  for (int t = 0; t < 8; ++t) {
    float xv = x[base + (size_t)t*D];
    float p[K];
    float den = EPS;
#pragma unroll
    for (int k = 0; k < K; ++k) {
      float df = xv - m[k];
      p[k] = __expf(nh[k]*df*df);
      den += p[k];
    }
    float rden = __builtin_amdgcn_rcpf(den);
    float acc = 0.f;
#pragma unroll
    for (int k = 0; k < K; ++k)
      acc += p[k] * (xv - e[k]) * r[k];
    out[base + (size_t)t*D] = acc * rden * isp;
  }
}

extern "C" void kernel_launch(void* const* d_in, const int* in_sizes, int n_in,
                              void* d_out, int out_size, void* d_ws, size_t ws_size,
                              hipStream_t stream) {
  const float* x        = (const float*)d_in[0];
  const float* mean     = (const float*)d_in[1];
  const float* variance = (const float*)d_in[2];
  // d_in[3] (prior): softmax over size-1 axis == 1 -> constant baked in.

  float* out = (float*)d_out;
  float* w   = (float*)d_ws;
  float* pt  = w;            // [K][B][TC][D] = 524288 floats
  float* p1  = pt + PSZ;
  float* p3  = p1 + PSZ;
  float* er  = p3 + PSZ;     // [B][D][K][2] = 65536 floats
  // every ws element is written before it is read -> no memset needed

  ucb_p1<<<B*4*TC, 256, 0, stream>>>(x, mean, variance, pt, p1, p3);
  ucb_fin<<<K*(D/16), 256, 0, stream>>>(pt, p1, p3, er);
  ucb_p2<<<B*64, 256, 0, stream>>>(x, mean, variance, er, out);
}